// Round 1
// baseline (545.328 us; speedup 1.0000x reference)
//
#include <hip/hip_runtime.h>
#include <cstdint>

#define INDIM 1024
#define OUTDIM 1024
#define NNZ 65536
#define M_ROWS 50000

typedef __bf16 bf16x8 __attribute__((ext_vector_type(8)));
typedef float f32x4 __attribute__((ext_vector_type(4)));
typedef unsigned int u32x4 __attribute__((ext_vector_type(4)));

// ---------------- scatter nnz values into dense fp32 W [OUTDIM][INDIM] ----------------
__global__ void scatter_w_kernel(const float* __restrict__ vals,
                                 const int* __restrict__ edge,
                                 float* __restrict__ Wf) {
    int e = blockIdx.x * blockDim.x + threadIdx.x;
    if (e < NNZ) {
        int r = edge[e];        // row  (output dim)
        int c = edge[NNZ + e];  // col  (input dim)
        atomicAdd(&Wf[r * INDIM + c], vals[e]);  // duplicates accumulate (matches .at[].add)
    }
}

// ---------------- fp32 W -> bf16 W (round-to-nearest-ish via +0x8000 truncate) --------
__global__ void cvt_w_kernel(const float* __restrict__ Wf,
                             unsigned short* __restrict__ Wb) {
    int i = blockIdx.x * blockDim.x + threadIdx.x;
    unsigned u = __builtin_bit_cast(unsigned, Wf[i]) + 0x8000u;
    Wb[i] = (unsigned short)(u >> 16);
}

// pack two fp32 -> one u32 holding two bf16 (a in low half = lower k index)
__device__ __forceinline__ unsigned pack_bf16x2(float a, float b) {
    unsigned ua = __builtin_bit_cast(unsigned, a) + 0x8000u;
    unsigned ub = __builtin_bit_cast(unsigned, b) + 0x8000u;
    return (ua >> 16) | (ub & 0xffff0000u);
}

__device__ __forceinline__ void async_copy16(const void* g, void* l) {
    __builtin_amdgcn_global_load_lds(
        (const __attribute__((address_space(1))) void*)g,
        (__attribute__((address_space(3))) void*)l, 16, 0, 0);
}

// ---------------- GEMM: out[M][1024] = bf16(x) @ Wb^T + bias -------------------------
// 128x128 tile, BK=32, 256 threads = 4 waves (2x2), each wave 4x4 frags of 16x16x32.
// A (x, fp32) staged manually with fused fp32->bf16 convert; B (Wb) via global_load_lds.
__global__ void __launch_bounds__(256)
gemm_bt_kernel(const float* __restrict__ X,
               const unsigned short* __restrict__ Wb,
               const float* __restrict__ bias,
               float* __restrict__ out) {
    __shared__ unsigned As[128 * 16];        // 128 rows x 32 bf16 (stored as 16 u32/row)
    __shared__ unsigned short Bs[128 * 32];  // 128 rows x 32 bf16

    const int t = threadIdx.x;
    const int w = t >> 6;        // wave id 0..3
    const int l = t & 63;        // lane
    const int wr = w >> 1;       // wave row group (0..1) -> 64 rows
    const int wc = w & 1;        // wave col group (0..1) -> 64 cols
    const int quad = l >> 4;     // 0..3
    const int lr = l & 15;       // 0..15
    const int m0 = blockIdx.y * 128;
    const int n0 = blockIdx.x * 128;

    // ---- A staging mapping: thread covers 16 consecutive floats of one tile row ----
    const int ar  = t >> 1;          // tile row 0..127
    const int akh = (t & 1) * 16;    // k offset within BK=32: 0 or 16
    int arow = m0 + ar;
    if (arow >= M_ROWS) arow = M_ROWS - 1;   // clamp tail (results masked at store)
    const float* aptr = X + (long)arow * INDIM + akh;
    unsigned* as_dst = &As[ar * 16 + (akh >> 1)];  // u32 units: 2 bf16 per u32

    f32x4 acc[4][4];
#pragma unroll
    for (int i = 0; i < 4; i++)
#pragma unroll
        for (int j = 0; j < 4; j++) acc[i][j] = (f32x4)0.0f;

    float biasv[4];
#pragma unroll
    for (int j = 0; j < 4; j++) biasv[j] = bias[n0 + wc * 64 + j * 16 + lr];

    for (int kt = 0; kt < INDIM; kt += 32) {
        // ---- B: 8 KB via async global->LDS, 2 chunks of 16 B per thread ----
#pragma unroll
        for (int i = 0; i < 2; i++) {
            int c = i * 256 + t;               // chunk 0..511
            int brow = c >> 2;                 // B tile row (n)
            int part = c & 3;                  // 16 B piece within the 64 B row
            const unsigned short* g = Wb + (long)(n0 + brow) * INDIM + kt + part * 8;
            // wave-uniform LDS base; HW writes base + lane*16
            char* lbase = (char*)Bs + (size_t)(i * 256 + w * 64) * 16;
            async_copy16(g, lbase);
        }

        // ---- A: 16 KB fp32 load -> bf16 pack -> 8 KB LDS ----
        const float* ap = aptr + kt;
        f32x4 f0 = *(const f32x4*)(ap);
        f32x4 f1 = *(const f32x4*)(ap + 4);
        f32x4 f2 = *(const f32x4*)(ap + 8);
        f32x4 f3 = *(const f32x4*)(ap + 12);
        u32x4 p0, p1;
        p0.x = pack_bf16x2(f0.x, f0.y);
        p0.y = pack_bf16x2(f0.z, f0.w);
        p0.z = pack_bf16x2(f1.x, f1.y);
        p0.w = pack_bf16x2(f1.z, f1.w);
        p1.x = pack_bf16x2(f2.x, f2.y);
        p1.y = pack_bf16x2(f2.z, f2.w);
        p1.z = pack_bf16x2(f3.x, f3.y);
        p1.w = pack_bf16x2(f3.z, f3.w);
        *(u32x4*)(as_dst)     = p0;
        *(u32x4*)(as_dst + 4) = p1;

        __syncthreads();  // drains vmcnt (async B) + lgkmcnt (A writes)

        // ---- fragments + 16 MFMA ----
        bf16x8 af[4], bf[4];
#pragma unroll
        for (int i = 0; i < 4; i++) {
            int row = wr * 64 + i * 16 + lr;
            af[i] = *(const bf16x8*)((const unsigned short*)As + row * 32 + quad * 8);
        }
#pragma unroll
        for (int j = 0; j < 4; j++) {
            int row = wc * 64 + j * 16 + lr;
            bf[j] = *(const bf16x8*)(Bs + row * 32 + quad * 8);
        }
#pragma unroll
        for (int i = 0; i < 4; i++)
#pragma unroll
            for (int j = 0; j < 4; j++)
                acc[i][j] = __builtin_amdgcn_mfma_f32_16x16x32_bf16(af[i], bf[j], acc[i][j], 0, 0, 0);

        __syncthreads();  // protect LDS before next-iter staging
    }

    // ---- epilogue: C/D layout col=lane&15, row=quad*4+reg ----
#pragma unroll
    for (int i = 0; i < 4; i++) {
#pragma unroll
        for (int j = 0; j < 4; j++) {
            int col = n0 + wc * 64 + j * 16 + lr;
#pragma unroll
            for (int r = 0; r < 4; r++) {
                int row = m0 + wr * 64 + i * 16 + quad * 4 + r;
                if (row < M_ROWS) {
                    out[(long)row * OUTDIM + col] = acc[i][j][r] + biasv[j];
                }
            }
        }
    }
}

extern "C" void kernel_launch(void* const* d_in, const int* in_sizes, int n_in,
                              void* d_out, int out_size, void* d_ws, size_t ws_size,
                              hipStream_t stream) {
    const float* x    = (const float*)d_in[0];
    const float* nnzw = (const float*)d_in[1];
    const float* bias = (const float*)d_in[2];
    const int* edge   = (const int*)d_in[3];
    float* out        = (float*)d_out;

    float* Wf         = (float*)d_ws;                                   // 4 MB
    unsigned short* Wb = (unsigned short*)((char*)d_ws + (size_t)OUTDIM * INDIM * 4);  // 2 MB

    // ws is poisoned 0xAA before every launch -> zero W accumulator every call
    hipMemsetAsync(Wf, 0, (size_t)OUTDIM * INDIM * sizeof(float), stream);

    scatter_w_kernel<<<NNZ / 256, 256, 0, stream>>>(nnzw, edge, Wf);
    cvt_w_kernel<<<(OUTDIM * INDIM) / 256, 256, 0, stream>>>(Wf, Wb);

    dim3 grid(OUTDIM / 128, (M_ROWS + 127) / 128);  // n-tile fastest: x-panel L2/L3 reuse
    gemm_bt_kernel<<<grid, 256, 0, stream>>>(x, Wb, bias, out);
}

// Round 2
// 519.328 us; speedup vs baseline: 1.0501x; 1.0501x over previous
//
#include <hip/hip_runtime.h>
#include <cstdint>

#define INDIM 1024
#define OUTDIM 1024
#define NNZ 65536
#define M_ROWS 50000

typedef __bf16 bf16x8 __attribute__((ext_vector_type(8)));
typedef float f32x4 __attribute__((ext_vector_type(4)));
typedef unsigned int u32x4 __attribute__((ext_vector_type(4)));

// ---------------- scatter nnz values into dense fp32 W [OUTDIM][INDIM] ----------------
__global__ void scatter_w_kernel(const float* __restrict__ vals,
                                 const int* __restrict__ edge,
                                 float* __restrict__ Wf) {
    int e = blockIdx.x * blockDim.x + threadIdx.x;
    if (e < NNZ) {
        int r = edge[e];        // row  (output dim)
        int c = edge[NNZ + e];  // col  (input dim)
        atomicAdd(&Wf[r * INDIM + c], vals[e]);  // duplicates accumulate (matches .at[].add)
    }
}

// ---------------- fp32 W -> bf16 W (round-to-nearest-ish via +0x8000 truncate) --------
__global__ void cvt_w_kernel(const float* __restrict__ Wf,
                             unsigned short* __restrict__ Wb) {
    int i = blockIdx.x * blockDim.x + threadIdx.x;
    unsigned u = __builtin_bit_cast(unsigned, Wf[i]) + 0x8000u;
    Wb[i] = (unsigned short)(u >> 16);
}

// pack two fp32 -> one u32 holding two bf16 (a in low half = lower k index)
__device__ __forceinline__ unsigned pack_bf16x2(float a, float b) {
    unsigned ua = __builtin_bit_cast(unsigned, a) + 0x8000u;
    unsigned ub = __builtin_bit_cast(unsigned, b) + 0x8000u;
    return (ua >> 16) | (ub & 0xffff0000u);
}

__device__ __forceinline__ void async_copy16(const void* g, void* l) {
    __builtin_amdgcn_global_load_lds(
        (const __attribute__((address_space(1))) void*)g,
        (__attribute__((address_space(3))) void*)l, 16, 0, 0);
}

// ---------------- GEMM: out[M][1024] = bf16(x) @ Wb^T + bias -------------------------
// 128x128 tile, BK=32, 256 threads = 4 waves (2x2), each wave 4x4 frags of 16x16x32.
// LDS layout XOR-swizzled: data chunk c (16 B) of row r lives at phys chunk c^((r>>1)&3).
//   -> frag ds_read_b128 becomes uniform 2-way (free) instead of 8-way.
// XCD-aware bid remap: the 8 n-blocks of one m-panel share bid%8 -> same XCD L2.
__global__ void __launch_bounds__(256)
gemm_bt_kernel(const float* __restrict__ X,
               const unsigned short* __restrict__ Wb,
               const float* __restrict__ bias,
               float* __restrict__ out) {
    __shared__ unsigned As[128 * 16];        // 128 rows x 32 bf16 (16 u32/row), swizzled
    __shared__ unsigned short Bs[128 * 32];  // 128 rows x 32 bf16, swizzled

    const int t = threadIdx.x;
    const int w = t >> 6;        // wave id 0..3
    const int l = t & 63;        // lane
    const int wr = w >> 1;       // wave row group (0..1) -> 64 rows
    const int wc = w & 1;        // wave col group (0..1) -> 64 cols
    const int quad = l >> 4;     // 0..3  (= data chunk index for frag reads)
    const int lr = l & 15;       // 0..15

    // ---- XCD-aware block remap: all 8 n-tiles of an m-panel get bid ≡ c (mod 8) ----
    const int bid = blockIdx.x;  // 0..3127
    int m_t, n_t;
    if (bid < 3072) {
        m_t = ((bid >> 6) << 3) + (bid & 7);  // 0..383
        n_t = (bid >> 3) & 7;
    } else {
        int r = bid - 3072;                   // 0..55
        m_t = 384 + (r >> 3);                 // 384..390
        n_t = r & 7;
    }
    const int m0 = m_t * 128;
    const int n0 = n_t * 128;

    // ---- A staging mapping: thread covers 16 consecutive floats of one tile row ----
    const int ar  = t >> 1;          // tile row 0..127
    const int ac0 = (t & 1) * 2;     // first data chunk (of 4 per row, 16 B each)
    const int as_sw = (ar >> 1) & 3; // row swizzle key
    int arow = m0 + ar;
    if (arow >= M_ROWS) arow = M_ROWS - 1;   // clamp tail (results masked at store)
    const float* aptr = X + (long)arow * INDIM + (t & 1) * 16;
    unsigned* as_row = &As[ar * 16];
    const int aph0 = (ac0 ^ as_sw) * 4;        // u32 offset of data chunk ac0
    const int aph1 = ((ac0 + 1) ^ as_sw) * 4;  // u32 offset of data chunk ac0+1

    f32x4 acc[4][4];
#pragma unroll
    for (int i = 0; i < 4; i++)
#pragma unroll
        for (int j = 0; j < 4; j++) acc[i][j] = (f32x4)0.0f;

    float biasv[4];
#pragma unroll
    for (int j = 0; j < 4; j++) biasv[j] = bias[n0 + wc * 64 + j * 16 + lr];

    // B staging source permutation (phys chunk = lane-linear; pick matching data chunk)
    int bsrc_off[2];
    int brow_[2];
#pragma unroll
    for (int i = 0; i < 2; i++) {
        int c_idx = i * 256 + t;             // phys chunk 0..511
        int brow = c_idx >> 2;               // tile row
        int pphys = c_idx & 3;
        int pdata = pphys ^ ((brow >> 1) & 3);
        brow_[i] = brow;
        bsrc_off[i] = pdata * 8;             // shorts
    }

    for (int kt = 0; kt < INDIM; kt += 32) {
        // ---- B: 8 KB via async global->LDS (source-permuted for swizzled layout) ----
#pragma unroll
        for (int i = 0; i < 2; i++) {
            const unsigned short* g = Wb + (long)(n0 + brow_[i]) * INDIM + kt + bsrc_off[i];
            char* lbase = (char*)Bs + (size_t)(i * 256 + w * 64) * 16;  // wave-uniform base
            async_copy16(g, lbase);
        }

        // ---- A: 16 KB fp32 load -> bf16 pack -> 8 KB LDS (swizzled ds_write) ----
        const float* ap = aptr + kt;
        f32x4 f0 = *(const f32x4*)(ap);
        f32x4 f1 = *(const f32x4*)(ap + 4);
        f32x4 f2 = *(const f32x4*)(ap + 8);
        f32x4 f3 = *(const f32x4*)(ap + 12);
        u32x4 p0, p1;
        p0.x = pack_bf16x2(f0.x, f0.y);
        p0.y = pack_bf16x2(f0.z, f0.w);
        p0.z = pack_bf16x2(f1.x, f1.y);
        p0.w = pack_bf16x2(f1.z, f1.w);
        p1.x = pack_bf16x2(f2.x, f2.y);
        p1.y = pack_bf16x2(f2.z, f2.w);
        p1.z = pack_bf16x2(f3.x, f3.y);
        p1.w = pack_bf16x2(f3.z, f3.w);
        *(u32x4*)(as_row + aph0) = p0;
        *(u32x4*)(as_row + aph1) = p1;

        __syncthreads();  // drains vmcnt (async B) + lgkmcnt (A writes)

        // ---- fragments + 16 MFMA (swizzled reads) ----
        bf16x8 af[4], bf[4];
#pragma unroll
        for (int i = 0; i < 4; i++) {
            int row = wr * 64 + i * 16 + lr;
            int ph = quad ^ ((row >> 1) & 3);
            af[i] = *(const bf16x8*)((const unsigned short*)As + row * 32 + ph * 8);
        }
#pragma unroll
        for (int j = 0; j < 4; j++) {
            int row = wc * 64 + j * 16 + lr;
            int ph = quad ^ ((row >> 1) & 3);
            bf[j] = *(const bf16x8*)(Bs + row * 32 + ph * 8);
        }
#pragma unroll
        for (int i = 0; i < 4; i++)
#pragma unroll
            for (int j = 0; j < 4; j++)
                acc[i][j] = __builtin_amdgcn_mfma_f32_16x16x32_bf16(af[i], bf[j], acc[i][j], 0, 0, 0);

        __syncthreads();  // protect LDS before next-iter staging
    }

    // ---- epilogue: C/D layout col=lane&15, row=quad*4+reg ----
#pragma unroll
    for (int i = 0; i < 4; i++) {
#pragma unroll
        for (int j = 0; j < 4; j++) {
            int col = n0 + wc * 64 + j * 16 + lr;
#pragma unroll
            for (int r = 0; r < 4; r++) {
                int row = m0 + wr * 64 + i * 16 + quad * 4 + r;
                if (row < M_ROWS) {
                    out[(long)row * OUTDIM + col] = acc[i][j][r] + biasv[j];
                }
            }
        }
    }
}

extern "C" void kernel_launch(void* const* d_in, const int* in_sizes, int n_in,
                              void* d_out, int out_size, void* d_ws, size_t ws_size,
                              hipStream_t stream) {
    const float* x    = (const float*)d_in[0];
    const float* nnzw = (const float*)d_in[1];
    const float* bias = (const float*)d_in[2];
    const int* edge   = (const int*)d_in[3];
    float* out        = (float*)d_out;

    float* Wf         = (float*)d_ws;                                   // 4 MB
    unsigned short* Wb = (unsigned short*)((char*)d_ws + (size_t)OUTDIM * INDIM * 4);  // 2 MB

    // ws is poisoned 0xAA before every launch -> zero W accumulator every call
    hipMemsetAsync(Wf, 0, (size_t)OUTDIM * INDIM * sizeof(float), stream);

    scatter_w_kernel<<<NNZ / 256, 256, 0, stream>>>(nnzw, edge, Wf);
    cvt_w_kernel<<<(OUTDIM * INDIM) / 256, 256, 0, stream>>>(Wf, Wb);

    // 391 m-tiles x 8 n-tiles = 3128 blocks, 1-D grid for explicit bid remap
    gemm_bt_kernel<<<dim3(3128), 256, 0, stream>>>(x, Wb, bias, out);
}